// Round 1
// baseline (330.008 us; speedup 1.0000x reference)
//
#include <hip/hip_runtime.h>
#include <hip/hip_bf16.h>

typedef unsigned short u16;
typedef unsigned int   u32;
typedef __bf16 bf16x8 __attribute__((ext_vector_type(8)));
typedef float  f32x4  __attribute__((ext_vector_type(4)));
typedef u32    u32x4  __attribute__((ext_vector_type(4)));

#define TRI_TOTAL 131328  // sum_{n=0}^{511} (n+1)

__device__ __forceinline__ float b2f(u16 u) {
    return __builtin_bit_cast(float, ((u32)u) << 16);
}
__device__ __forceinline__ u16 f2b(float f) {  // RNE f32->bf16
    u32 u = __builtin_bit_cast(u32, f);
    return (u16)((u + 0x7fffu + ((u >> 16) & 1u)) >> 16);
}

// ---------------- LayerNorm -> xn (bf16) ----------------
__global__ void __launch_bounds__(256) ln_kernel(const float* __restrict__ x,
                                                 const float* __restrict__ g,
                                                 const float* __restrict__ b,
                                                 u16* __restrict__ xn) {
    int n = blockIdx.x, t = threadIdx.x;
    float v = x[n * 256 + t];
    __shared__ float red[4];
    float s = v;
    #pragma unroll
    for (int o = 32; o >= 1; o >>= 1) s += __shfl_xor(s, o);
    if ((t & 63) == 0) red[t >> 6] = s;
    __syncthreads();
    float mu = (red[0] + red[1] + red[2] + red[3]) * (1.0f / 256.0f);
    float d = v - mu;
    __syncthreads();
    float s2 = d * d;
    #pragma unroll
    for (int o = 32; o >= 1; o >>= 1) s2 += __shfl_xor(s2, o);
    if ((t & 63) == 0) red[t >> 6] = s2;
    __syncthreads();
    float var = (red[0] + red[1] + red[2] + red[3]) * (1.0f / 256.0f);
    float y = d * rsqrtf(var + 1e-5f) * g[t] + b[t];
    xn[n * 256 + t] = f2b(y);
}

// ---------------- Per-relative-index projections ----------------
// Q/V: qd[r,m] = xn[m] @ W[r], needed m in [0, 512-r).  Stored at tri(r+m)+m.
// K:   kd[r,pos] = xn[pos] @ Wk[r], needed pos in [511-r, 512).
//      Stored at tri(pos) + (pos-(511-r)).
// Block: one (which, r, col-slice of 64). W-slice LDS-resident (transposed,
// swizzled bf16); loop m-tiles of 64 rows with reg-staged A prefetch (T14).
__global__ void __launch_bounds__(128, 2) proj_kernel(
        const u16* __restrict__ xn,
        const float* __restrict__ Wq, const float* __restrict__ Wk,
        const float* __restrict__ Wv,
        u16* __restrict__ Qa, u16* __restrict__ Ka, u16* __restrict__ Va) {
    __shared__ u16 Wl[64 * 256];   // [col][k] bf16, XOR-swizzled rows
    __shared__ u16 Al[64 * 256];   // [row][k] bf16, XOR-swizzled rows

    int bid = blockIdx.x;
    int which = bid >> 11;          // 0=Q,1=K,2=V (2048 blocks each)
    int rr = bid & 2047;
    int r  = rr >> 2;
    int cs = rr & 3;
    const float* W = (which == 0) ? Wq : ((which == 1) ? Wk : Wv);
    u16* Out       = (which == 0) ? Qa : ((which == 1) ? Ka : Va);
    int rows  = (which == 1) ? (r + 1) : (512 - r);
    int pbase = (which == 1) ? (511 - r) : 0;   // xn position = pbase + ml
    int nbase = (which == 1) ? (511 - r) : r;   // attn row n = nbase + ml

    int t = threadIdx.x;
    int c0 = cs * 64;

    // stage W[r][:, c0:c0+64] -> Wl[c][k] bf16 (transposed), swizzled
    {
        int c  = t & 63;
        int kh = (t >> 6) << 7;     // 0 or 128
        const float* wp = W + ((size_t)r << 16) + (size_t)(c0 + c);
        char* wrow = (char*)Wl + c * 512;
        int sw = (c & 7) << 4;
        for (int kk = 0; kk < 16; ++kk) {
            int kbase = kh + kk * 8;
            u32x4 tmp;
            #pragma unroll
            for (int i = 0; i < 4; ++i) {
                float flo = wp[(size_t)(kbase + 2 * i) << 8];
                float fhi = wp[(size_t)(kbase + 2 * i + 1) << 8];
                tmp[i] = (u32)f2b(flo) | ((u32)f2b(fhi) << 16);
            }
            *reinterpret_cast<u32x4*>(wrow + ((kbase * 2) ^ sw)) = tmp;
        }
    }

    // A-tile staging state: thread covers 256B (half a row)
    int arow  = t >> 1;
    int ahalf = (t & 1) << 8;       // byte offset in row
    int asw   = (arow & 7) << 4;
    u32x4 areg[16];

    auto a_load = [&](int m0) {
        int gpos = pbase + m0 + arow;
        if (gpos > 511) gpos = 511;
        const char* src = (const char*)xn + (size_t)gpos * 512 + ahalf;
        #pragma unroll
        for (int j = 0; j < 16; ++j)
            areg[j] = *reinterpret_cast<const u32x4*>(src + j * 16);
    };

    int wv  = t >> 6;               // wave id: rows [32*wv, 32*wv+32)
    int L   = t & 63;
    int l15 = L & 15, l4 = L >> 4;
    int rbase = wv * 32;

    a_load(0);
    for (int m0 = 0; m0 < rows; m0 += 64) {
        __syncthreads();            // prev compute done (Al free); W ready
        {   // write staged A-tile (swizzled)
            char* dst = (char*)Al + arow * 512;
            #pragma unroll
            for (int j = 0; j < 16; ++j)
                *reinterpret_cast<u32x4*>(dst + ((ahalf + j * 16) ^ asw)) = areg[j];
        }
        __syncthreads();            // Al visible
        if (m0 + 64 < rows) a_load(m0 + 64);   // prefetch flies under MFMA

        f32x4 acc[2][4] = {};
        #pragma unroll
        for (int ks = 0; ks < 8; ++ks) {
            int kb = ks * 64 + l4 * 16;   // byte offset of lane's 8 bf16
            bf16x8 a[2], b[4];
            #pragma unroll
            for (int rf = 0; rf < 2; ++rf) {
                int row = rbase + rf * 16 + l15;
                a[rf] = *reinterpret_cast<const bf16x8*>(
                    (const char*)Al + row * 512 + (kb ^ ((row & 7) << 4)));
            }
            #pragma unroll
            for (int cf = 0; cf < 4; ++cf) {
                int col = cf * 16 + l15;
                b[cf] = *reinterpret_cast<const bf16x8*>(
                    (const char*)Wl + col * 512 + (kb ^ ((col & 7) << 4)));
            }
            #pragma unroll
            for (int rf = 0; rf < 2; ++rf)
                #pragma unroll
                for (int cf = 0; cf < 4; ++cf)
                    acc[rf][cf] = __builtin_amdgcn_mfma_f32_16x16x32_bf16(
                        a[rf], b[cf], acc[rf][cf], 0, 0, 0);
        }
        // store to packed attention layout
        #pragma unroll
        for (int rf = 0; rf < 2; ++rf) {
            #pragma unroll
            for (int j = 0; j < 4; ++j) {
                int ml = m0 + rbase + rf * 16 + l4 * 4 + j;
                if (ml < rows) {
                    int nout = nbase + ml;
                    size_t prow = (size_t)(nout * (nout + 1) / 2) + (size_t)ml;
                    u16* op = Out + prow * 256 + c0 + l15;
                    #pragma unroll
                    for (int cf = 0; cf < 4; ++cf)
                        op[cf * 16] = f2b(acc[rf][cf][j]);
                }
            }
        }
    }
}

// ---------------- per-row attention ----------------
// Block = one query row n. Band rows tri(n)..tri(n)+n hold per-pair q,k,v.
__global__ void __launch_bounds__(256) attn_kernel(const u16* __restrict__ Qa,
                                                   const u16* __restrict__ Ka,
                                                   const u16* __restrict__ Va,
                                                   float* __restrict__ ao) {
    int n = blockIdx.x, t = threadIdx.x;
    __shared__ float pbuf[512 * 9];   // [m][h] padded pitch 9
    __shared__ float linv[8];
    int band = n + 1;
    size_t rb = (size_t)(n * (n + 1) / 2);

    // scores: thread = (m-inner, h)
    int h = t & 7, mi = t >> 3;
    for (int m0 = 0; m0 < band; m0 += 32) {
        int m = m0 + mi;
        float d = -1e30f;
        if (m < band) {
            const char* qp = (const char*)Qa + (rb + m) * 512 + h * 64;
            const char* kp = (const char*)Ka + (rb + m) * 512 + h * 64;
            float acc = 0.f;
            #pragma unroll
            for (int cch = 0; cch < 4; ++cch) {
                u32x4 qv = *reinterpret_cast<const u32x4*>(qp + cch * 16);
                u32x4 kv = *reinterpret_cast<const u32x4*>(kp + cch * 16);
                #pragma unroll
                for (int i = 0; i < 4; ++i) {
                    float ql = __builtin_bit_cast(float, qv[i] << 16);
                    float qh = __builtin_bit_cast(float, qv[i] & 0xffff0000u);
                    float kl = __builtin_bit_cast(float, kv[i] << 16);
                    float kh = __builtin_bit_cast(float, kv[i] & 0xffff0000u);
                    acc += ql * kl + qh * kh;
                }
            }
            d = acc * 0.17677669529663687f;  // 1/sqrt(32)
        }
        pbuf[m * 9 + h] = d;
    }
    __syncthreads();

    // softmax per head: wave wv handles heads wv and wv+4
    int wv = t >> 6, L = t & 63;
    for (int s = 0; s < 2; ++s) {
        int hh = wv + s * 4;
        float mx = -1e30f;
        for (int m = L; m < band; m += 64) mx = fmaxf(mx, pbuf[m * 9 + hh]);
        #pragma unroll
        for (int o = 32; o >= 1; o >>= 1) mx = fmaxf(mx, __shfl_xor(mx, o));
        float sum = 0.f;
        for (int m = L; m < band; m += 64) {
            float p = __expf(pbuf[m * 9 + hh] - mx);
            pbuf[m * 9 + hh] = p;
            sum += p;
        }
        #pragma unroll
        for (int o = 32; o >= 1; o >>= 1) sum += __shfl_xor(sum, o);
        if (L == 0) linv[hh] = 1.0f / sum;
    }
    __syncthreads();

    // PV: thread = output channel t = h*32+e
    int h2 = t >> 5;
    const char* vp = (const char*)Va + rb * 512 + (size_t)t * 2;
    const float* pb = pbuf + h2;
    float a0 = 0, a1 = 0, a2 = 0, a3 = 0;
    int m = 0;
    for (; m + 4 <= band; m += 4) {
        a0 += pb[(m + 0) * 9] * b2f(*(const u16*)(vp + (size_t)(m + 0) * 512));
        a1 += pb[(m + 1) * 9] * b2f(*(const u16*)(vp + (size_t)(m + 1) * 512));
        a2 += pb[(m + 2) * 9] * b2f(*(const u16*)(vp + (size_t)(m + 2) * 512));
        a3 += pb[(m + 3) * 9] * b2f(*(const u16*)(vp + (size_t)(m + 3) * 512));
    }
    for (; m < band; ++m)
        a0 += pb[m * 9] * b2f(*(const u16*)(vp + (size_t)m * 512));
    ao[n * 256 + t] = ((a0 + a1) + (a2 + a3)) * linv[h2];
}

// ---------------- output projection ----------------
__global__ void __launch_bounds__(256) outproj_kernel(const float* __restrict__ ao,
                                                      const float* __restrict__ Wo,
                                                      const float* __restrict__ bo,
                                                      float* __restrict__ out) {
    int n = blockIdx.x, e = threadIdx.x;
    const float* a = ao + n * 256;
    float c0 = bo[e], c1 = 0, c2 = 0, c3 = 0;
    for (int c = 0; c < 256; c += 4) {
        c0 += a[c + 0] * Wo[(c + 0) * 256 + e];
        c1 += a[c + 1] * Wo[(c + 1) * 256 + e];
        c2 += a[c + 2] * Wo[(c + 2) * 256 + e];
        c3 += a[c + 3] * Wo[(c + 3) * 256 + e];
    }
    out[n * 256 + e] = (c0 + c1) + (c2 + c3);
}

extern "C" void kernel_launch(void* const* d_in, const int* in_sizes, int n_in,
                              void* d_out, int out_size, void* d_ws, size_t ws_size,
                              hipStream_t stream) {
    const float* x     = (const float*)d_in[0];
    const float* Wq    = (const float*)d_in[1];
    const float* Wk    = (const float*)d_in[2];
    const float* Wv    = (const float*)d_in[3];
    const float* gamma = (const float*)d_in[4];
    const float* beta  = (const float*)d_in[5];
    const float* Wo    = (const float*)d_in[6];
    const float* bo    = (const float*)d_in[7];
    float* out = (float*)d_out;

    char* ws = (char*)d_ws;
    u16* xn = (u16*)ws;
    size_t off = (size_t)512 * 256 * 2;
    u16* Qa = (u16*)(ws + off); off += (size_t)TRI_TOTAL * 256 * 2;
    u16* Ka = (u16*)(ws + off); off += (size_t)TRI_TOTAL * 256 * 2;
    u16* Va = (u16*)(ws + off); off += (size_t)TRI_TOTAL * 256 * 2;
    float* ao = (float*)(ws + off);

    ln_kernel<<<512, 256, 0, stream>>>(x, gamma, beta, xn);
    proj_kernel<<<6144, 128, 0, stream>>>(xn, Wq, Wk, Wv, Qa, Ka, Va);
    attn_kernel<<<512, 256, 0, stream>>>(Qa, Ka, Va, ao);
    outproj_kernel<<<512, 256, 0, stream>>>(ao, Wo, bo, out);
}

// Round 2
// 290.062 us; speedup vs baseline: 1.1377x; 1.1377x over previous
//
#include <hip/hip_runtime.h>
#include <hip/hip_bf16.h>

typedef unsigned short u16;
typedef unsigned int   u32;
typedef __bf16 bf16x8 __attribute__((ext_vector_type(8)));
typedef float  f32x4  __attribute__((ext_vector_type(4)));
typedef u32    u32x4  __attribute__((ext_vector_type(4)));

#define TRI_TOTAL 131328  // sum_{n=0}^{511} (n+1)

__device__ __forceinline__ float b2f(u16 u) {
    return __builtin_bit_cast(float, ((u32)u) << 16);
}
__device__ __forceinline__ u16 f2b(float f) {  // RNE f32->bf16
    u32 u = __builtin_bit_cast(u32, f);
    return (u16)((u + 0x7fffu + ((u >> 16) & 1u)) >> 16);
}

// ---------------- LayerNorm -> xn (bf16) ----------------
__global__ void __launch_bounds__(256) ln_kernel(const float* __restrict__ x,
                                                 const float* __restrict__ g,
                                                 const float* __restrict__ b,
                                                 u16* __restrict__ xn) {
    int n = blockIdx.x, t = threadIdx.x;
    float v = x[n * 256 + t];
    __shared__ float red[4];
    float s = v;
    #pragma unroll
    for (int o = 32; o >= 1; o >>= 1) s += __shfl_xor(s, o);
    if ((t & 63) == 0) red[t >> 6] = s;
    __syncthreads();
    float mu = (red[0] + red[1] + red[2] + red[3]) * (1.0f / 256.0f);
    float d = v - mu;
    __syncthreads();
    float s2 = d * d;
    #pragma unroll
    for (int o = 32; o >= 1; o >>= 1) s2 += __shfl_xor(s2, o);
    if ((t & 63) == 0) red[t >> 6] = s2;
    __syncthreads();
    float var = (red[0] + red[1] + red[2] + red[3]) * (1.0f / 256.0f);
    float y = d * rsqrtf(var + 1e-5f) * g[t] + b[t];
    xn[n * 256 + t] = f2b(y);
}

// ---------------- Per-relative-index projections (v2) ----------------
// Q/V: qd[r,m] = xn[m] @ W[r], needed m in [0, 512-r).  Stored at tri(r+m)+m.
// K:   kd[r,pos] = xn[pos] @ Wk[r], needed pos in [511-r, 512).
//      Stored at tri(pos) + (pos-(511-r)).
// v2: only the W slice lives in LDS (32 KB -> 5 blocks/CU, 10 waves/CU).
// A-fragments load straight from global xn (256 KB, L2-resident) as 16B
// dwordx4 -- no Al staging, no per-m-tile barrier. One barrier per block.
__global__ void __launch_bounds__(128) proj_kernel(
        const u16* __restrict__ xn,
        const float* __restrict__ Wq, const float* __restrict__ Wk,
        const float* __restrict__ Wv,
        u16* __restrict__ Qa, u16* __restrict__ Ka, u16* __restrict__ Va) {
    __shared__ u16 Wl[64 * 256];   // [col][k] bf16, XOR-swizzled rows

    int bid = blockIdx.x;
    int which = bid >> 11;          // 0=Q,1=K,2=V (2048 blocks each)
    int rr = bid & 2047;
    int r  = rr >> 2;
    int cs = rr & 3;
    const float* W = (which == 0) ? Wq : ((which == 1) ? Wk : Wv);
    u16* Out       = (which == 0) ? Qa : ((which == 1) ? Ka : Va);
    int rows  = (which == 1) ? (r + 1) : (512 - r);
    int pbase = (which == 1) ? (511 - r) : 0;   // xn position = pbase + ml
    int nbase = (which == 1) ? (511 - r) : r;   // attn row n = nbase + ml

    int t = threadIdx.x;
    int c0 = cs * 64;

    // stage W[r][:, c0:c0+64] -> Wl[c][k] bf16 (transposed), swizzled
    {
        int c  = t & 63;
        int kh = (t >> 6) << 7;     // 0 or 128
        const float* wp = W + ((size_t)r << 16) + (size_t)(c0 + c);
        char* wrow = (char*)Wl + c * 512;
        int sw = (c & 7) << 4;
        for (int kk = 0; kk < 16; ++kk) {
            int kbase = kh + kk * 8;
            u32x4 tmp;
            #pragma unroll
            for (int i = 0; i < 4; ++i) {
                float flo = wp[(size_t)(kbase + 2 * i) << 8];
                float fhi = wp[(size_t)(kbase + 2 * i + 1) << 8];
                tmp[i] = (u32)f2b(flo) | ((u32)f2b(fhi) << 16);
            }
            *reinterpret_cast<u32x4*>(wrow + ((kbase * 2) ^ sw)) = tmp;
        }
    }
    __syncthreads();                // Wl ready; no more barriers this block

    int wv  = t >> 6;               // wave id: rows [32*wv, 32*wv+32)
    int L   = t & 63;
    int l15 = L & 15, l4 = L >> 4;
    int rbase = wv * 32;

    for (int m0 = 0; m0 < rows; m0 += 64) {
        f32x4 acc[2][4] = {};
        #pragma unroll
        for (int ks = 0; ks < 8; ++ks) {
            int kb = ks * 64 + l4 * 16;   // byte offset of lane's 8 bf16
            bf16x8 a[2], b[4];
            #pragma unroll
            for (int rf = 0; rf < 2; ++rf) {
                int ml = m0 + rbase + rf * 16 + l15;
                int gpos = pbase + ml;
                if (gpos > 511) gpos = 511;   // tail rows: load dummy, masked at store
                a[rf] = *reinterpret_cast<const bf16x8*>(
                    (const char*)xn + (size_t)gpos * 512 + kb);
            }
            #pragma unroll
            for (int cf = 0; cf < 4; ++cf) {
                int col = cf * 16 + l15;
                b[cf] = *reinterpret_cast<const bf16x8*>(
                    (const char*)Wl + col * 512 + (kb ^ ((col & 7) << 4)));
            }
            #pragma unroll
            for (int rf = 0; rf < 2; ++rf)
                #pragma unroll
                for (int cf = 0; cf < 4; ++cf)
                    acc[rf][cf] = __builtin_amdgcn_mfma_f32_16x16x32_bf16(
                        a[rf], b[cf], acc[rf][cf], 0, 0, 0);
        }
        // store to packed attention layout
        #pragma unroll
        for (int rf = 0; rf < 2; ++rf) {
            #pragma unroll
            for (int j = 0; j < 4; ++j) {
                int ml = m0 + rbase + rf * 16 + l4 * 4 + j;
                if (ml < rows) {
                    int nout = nbase + ml;
                    size_t prow = (size_t)(nout * (nout + 1) / 2) + (size_t)ml;
                    u16* op = Out + prow * 256 + c0 + l15;
                    #pragma unroll
                    for (int cf = 0; cf < 4; ++cf)
                        op[cf * 16] = f2b(acc[rf][cf][j]);
                }
            }
        }
    }
}

// ---------------- per-row attention ----------------
// Block = one query row n. Band rows tri(n)..tri(n)+n hold per-pair q,k,v.
__global__ void __launch_bounds__(256) attn_kernel(const u16* __restrict__ Qa,
                                                   const u16* __restrict__ Ka,
                                                   const u16* __restrict__ Va,
                                                   float* __restrict__ ao) {
    int n = blockIdx.x, t = threadIdx.x;
    __shared__ float pbuf[512 * 9];   // [m][h] padded pitch 9
    __shared__ float linv[8];
    int band = n + 1;
    size_t rb = (size_t)(n * (n + 1) / 2);

    // scores: thread = (m-inner, h)
    int h = t & 7, mi = t >> 3;
    for (int m0 = 0; m0 < band; m0 += 32) {
        int m = m0 + mi;
        float d = -1e30f;
        if (m < band) {
            const char* qp = (const char*)Qa + (rb + m) * 512 + h * 64;
            const char* kp = (const char*)Ka + (rb + m) * 512 + h * 64;
            float acc = 0.f;
            #pragma unroll
            for (int cch = 0; cch < 4; ++cch) {
                u32x4 qv = *reinterpret_cast<const u32x4*>(qp + cch * 16);
                u32x4 kv = *reinterpret_cast<const u32x4*>(kp + cch * 16);
                #pragma unroll
                for (int i = 0; i < 4; ++i) {
                    float ql = __builtin_bit_cast(float, qv[i] << 16);
                    float qh = __builtin_bit_cast(float, qv[i] & 0xffff0000u);
                    float kl = __builtin_bit_cast(float, kv[i] << 16);
                    float kh = __builtin_bit_cast(float, kv[i] & 0xffff0000u);
                    acc += ql * kl + qh * kh;
                }
            }
            d = acc * 0.17677669529663687f;  // 1/sqrt(32)
        }
        pbuf[m * 9 + h] = d;
    }
    __syncthreads();

    // softmax per head: wave wv handles heads wv and wv+4
    int wv = t >> 6, L = t & 63;
    for (int s = 0; s < 2; ++s) {
        int hh = wv + s * 4;
        float mx = -1e30f;
        for (int m = L; m < band; m += 64) mx = fmaxf(mx, pbuf[m * 9 + hh]);
        #pragma unroll
        for (int o = 32; o >= 1; o >>= 1) mx = fmaxf(mx, __shfl_xor(mx, o));
        float sum = 0.f;
        for (int m = L; m < band; m += 64) {
            float p = __expf(pbuf[m * 9 + hh] - mx);
            pbuf[m * 9 + hh] = p;
            sum += p;
        }
        #pragma unroll
        for (int o = 32; o >= 1; o >>= 1) sum += __shfl_xor(sum, o);
        if (L == 0) linv[hh] = 1.0f / sum;
    }
    __syncthreads();

    // PV: thread = output channel t = h*32+e
    int h2 = t >> 5;
    const char* vp = (const char*)Va + rb * 512 + (size_t)t * 2;
    const float* pb = pbuf + h2;
    float a0 = 0, a1 = 0, a2 = 0, a3 = 0;
    int m = 0;
    for (; m + 4 <= band; m += 4) {
        a0 += pb[(m + 0) * 9] * b2f(*(const u16*)(vp + (size_t)(m + 0) * 512));
        a1 += pb[(m + 1) * 9] * b2f(*(const u16*)(vp + (size_t)(m + 1) * 512));
        a2 += pb[(m + 2) * 9] * b2f(*(const u16*)(vp + (size_t)(m + 2) * 512));
        a3 += pb[(m + 3) * 9] * b2f(*(const u16*)(vp + (size_t)(m + 3) * 512));
    }
    for (; m < band; ++m)
        a0 += pb[m * 9] * b2f(*(const u16*)(vp + (size_t)m * 512));
    ao[n * 256 + t] = ((a0 + a1) + (a2 + a3)) * linv[h2];
}

// ---------------- output projection ----------------
__global__ void __launch_bounds__(256) outproj_kernel(const float* __restrict__ ao,
                                                      const float* __restrict__ Wo,
                                                      const float* __restrict__ bo,
                                                      float* __restrict__ out) {
    int n = blockIdx.x, e = threadIdx.x;
    const float* a = ao + n * 256;
    float c0 = bo[e], c1 = 0, c2 = 0, c3 = 0;
    for (int c = 0; c < 256; c += 4) {
        c0 += a[c + 0] * Wo[(c + 0) * 256 + e];
        c1 += a[c + 1] * Wo[(c + 1) * 256 + e];
        c2 += a[c + 2] * Wo[(c + 2) * 256 + e];
        c3 += a[c + 3] * Wo[(c + 3) * 256 + e];
    }
    out[n * 256 + e] = (c0 + c1) + (c2 + c3);
}

extern "C" void kernel_launch(void* const* d_in, const int* in_sizes, int n_in,
                              void* d_out, int out_size, void* d_ws, size_t ws_size,
                              hipStream_t stream) {
    const float* x     = (const float*)d_in[0];
    const float* Wq    = (const float*)d_in[1];
    const float* Wk    = (const float*)d_in[2];
    const float* Wv    = (const float*)d_in[3];
    const float* gamma = (const float*)d_in[4];
    const float* beta  = (const float*)d_in[5];
    const float* Wo    = (const float*)d_in[6];
    const float* bo    = (const float*)d_in[7];
    float* out = (float*)d_out;

    char* ws = (char*)d_ws;
    u16* xn = (u16*)ws;
    size_t off = (size_t)512 * 256 * 2;
    u16* Qa = (u16*)(ws + off); off += (size_t)TRI_TOTAL * 256 * 2;
    u16* Ka = (u16*)(ws + off); off += (size_t)TRI_TOTAL * 256 * 2;
    u16* Va = (u16*)(ws + off); off += (size_t)TRI_TOTAL * 256 * 2;
    float* ao = (float*)(ws + off);

    ln_kernel<<<512, 256, 0, stream>>>(x, gamma, beta, xn);
    proj_kernel<<<6144, 128, 0, stream>>>(xn, Wq, Wk, Wv, Qa, Ka, Va);
    attn_kernel<<<512, 256, 0, stream>>>(Qa, Ka, Va, ao);
    outproj_kernel<<<512, 256, 0, stream>>>(ao, Wo, bo, out);
}